// Round 9
// baseline (128.369 us; speedup 1.0000x reference)
//
#include <hip/hip_runtime.h>
#include <math.h>

// Problem constants
constexpr int N = 8, C = 128, H = 64, W = 64;
constexpr int PIX = H * W;            // 4096
constexpr int KK = 49;                // 7x7 window

// ws layout (floats)
constexpr size_t M_OFF    = 0;                         // M = W1^T W2
constexpr size_t WT3_OFF  = 16384;                     // W3^T [k][o]
constexpr size_t Z_OFF    = 65536;                     // z = M^T x
constexpr size_t YSZ      = (size_t)N * C * PIX;       // 4,194,304
constexpr size_t SIMSZ1   = (size_t)N * H * KK * W;    // 1,605,632
constexpr size_t SIMP_OFF = Z_OFF + YSZ;               // 4 partial sims
constexpr size_t ATT_OFF  = SIMP_OFF + 4 * SIMSZ1;     // attn fp32
constexpr size_t U_OFF    = ATT_OFF + SIMSZ1;          // u = PV(x)

constexpr int SLW = 76;   // padded stage row width; image col v -> col 4+v

// ---------------------------------------------------------------------------
// K0: prep. Blocks 0..63: M[a][b] = sum_c W1[c][a]*W2[c][b].
//     Blocks 64..67: Wt3[c][o] = W3[o][c].
// ---------------------------------------------------------------------------
__global__ __launch_bounds__(256) void prep(const float* __restrict__ w1,
                                            const float* __restrict__ w2,
                                            const float* __restrict__ w3,
                                            float* __restrict__ Mout,
                                            float* __restrict__ wt3) {
    int bid = blockIdx.x, tid = threadIdx.x;
    if (bid < 64) {
        int a = bid * 2 + (tid >> 7);
        int b = tid & 127;
        float s = 0.f;
        for (int c = 0; c < 128; c++)
            s = fmaf(w1[c * 128 + a], w2[c * 128 + b], s);
        Mout[a * 128 + b] = s;
    } else {
        int base = (bid - 64) * 4096;
        for (int i = tid; i < 4096; i += 256) {
            int idx = base + i;
            int o = idx & 127, c = idx >> 7;
            wt3[idx] = w3[o * 128 + c];
        }
    }
}

// ---------------------------------------------------------------------------
// K1: 1x1-conv GEMM. Block tile: 128 oc x 64 px, K=128 chunked by 32.
// ---------------------------------------------------------------------------
__global__ __launch_bounds__(256) void convk(const float* __restrict__ A,
                                             const float* __restrict__ Bsrc,
                                             float* __restrict__ Yout) {
    __shared__ float la[32 * 136];
    __shared__ float lb[32 * 72];

    int bid = blockIdx.x;
    int pt  = bid & 63;
    int n   = bid >> 6;
    int p0  = pt * 64;

    const float* B = Bsrc + (size_t)n * C * PIX;
    float*       Y = Yout + (size_t)n * C * PIX;

    int tid = threadIdx.x;
    int tx  = tid & 15, ty = tid >> 4;
    int oc0 = ty * 8, px0 = tx * 4;

    float acc[8][4];
#pragma unroll
    for (int i = 0; i < 8; i++)
#pragma unroll
        for (int j = 0; j < 4; j++) acc[i][j] = 0.f;

    for (int kk = 0; kk < 128; kk += 32) {
#pragma unroll
        for (int i = 0; i < 4; i++) {
            int q   = tid + i * 256;
            int row = q >> 5;
            int c4  = (q & 31) * 4;
            *(float4*)&la[row * 136 + c4] =
                *(const float4*)&A[(kk + row) * 128 + c4];
        }
#pragma unroll
        for (int i = 0; i < 2; i++) {
            int q   = tid + i * 256;
            int row = q >> 4;
            int c4  = (q & 15) * 4;
            *(float4*)&lb[row * 72 + c4] =
                *(const float4*)&B[(size_t)(kk + row) * PIX + p0 + c4];
        }
        __syncthreads();

#pragma unroll 8
        for (int k = 0; k < 32; k++) {
            float4 a0 = *(float4*)&la[k * 136 + oc0];
            float4 a1 = *(float4*)&la[k * 136 + oc0 + 4];
            float4 b0 = *(float4*)&lb[k * 72 + px0];
            float a[8] = {a0.x, a0.y, a0.z, a0.w, a1.x, a1.y, a1.z, a1.w};
            float b[4] = {b0.x, b0.y, b0.z, b0.w};
#pragma unroll
            for (int i = 0; i < 8; i++)
#pragma unroll
                for (int j = 0; j < 4; j++)
                    acc[i][j] = fmaf(a[i], b[j], acc[i][j]);
        }
        __syncthreads();
    }

#pragma unroll
    for (int i = 0; i < 8; i++) {
        float4 v = make_float4(acc[i][0], acc[i][1], acc[i][2], acc[i][3]);
        *(float4*)&Y[(size_t)(oc0 + i) * PIX + p0 + px0] = v;
    }
}

// ---------------------------------------------------------------------------
// K2: partial sim.  Block = (di, cb, g): grid 3584 = 7 x 4 x 128.
// Stages 32 channels x 4 window rows ONCE (c-major, conflict-free), computes
// sim contribution of its 32 channels for its di, reduces over 4 waves,
// writes simp[cb][n][h][k=di*7+dj][w].  3 barriers, no loops over chunks.
// ---------------------------------------------------------------------------
__global__ __launch_bounds__(256) void simk4(const float* __restrict__ z,
                                             const float* __restrict__ x,
                                             float* __restrict__ simp) {
    __shared__ __align__(16) float st[32 * 4 * SLW];   // 9728 f = 38.9 KB (>= red 5376)

    int bid = blockIdx.x;
    int di  = bid >> 9;            // 0..6
    int cb  = (bid >> 7) & 3;      // c-quarter
    int g   = bid & 127;
    int n   = g >> 4;
    int hq  = g & 15;
    int h0  = hq * 4;

    int tid  = threadIdx.x;
    int wid  = tid >> 6;
    int lane = tid & 63;
    int r = lane >> 4, w4 = lane & 15, wpx = w4 * 4;

    const float* zb = z + (size_t)n * C * PIX;
    const float* xb = x + (size_t)n * C * PIX;

    // halo zero (32c x 4row x 8 cols) + stage interior (2048 f4, 8/thread)
    for (int idx = tid; idx < 32 * 4 * 8; idx += 256) {
        int col8 = idx & 7;
        int row  = (idx >> 3) & 3;
        int c    = idx >> 5;
        int col  = (col8 < 4) ? col8 : 64 + col8;
        st[(c * 4 + row) * SLW + col] = 0.f;
    }
#pragma unroll
    for (int i = 0; i < 8; i++) {
        int q   = tid + i * 256;
        int w16 = q & 15;
        int row = (q >> 4) & 3;
        int c   = q >> 6;             // 0..31
        int hh  = h0 + di - 3 + row;
        float4 v = make_float4(0.f, 0.f, 0.f, 0.f);
        if ((unsigned)hh < 64u)
            v = *(const float4*)&xb[(size_t)(cb * 32 + c) * PIX + hh * 64 + w16 * 4];
        *(float4*)&st[(c * 4 + row) * SLW + 4 + w16 * 4] = v;
    }
    __syncthreads();

    float acc[7][4];
#pragma unroll
    for (int dj = 0; dj < 7; dj++)
#pragma unroll
        for (int j = 0; j < 4; j++) acc[dj][j] = 0.f;

#pragma unroll
    for (int c = 0; c < 8; c++) {
        int cl    = wid * 8 + c;                 // 0..31 in block
        int cglob = cb * 32 + cl;
        float4 z4 = *(const float4*)&zb[(size_t)cglob * PIX + (h0 + r) * 64 + wpx];
        const float* rp = &st[(cl * 4 + r) * SLW + wpx];
        float rw[12];
        *(float4*)&rw[0] = *(const float4*)&rp[0];
        *(float4*)&rw[4] = *(const float4*)&rp[4];
        *(float4*)&rw[8] = *(const float4*)&rp[8];
        const float* zp = (const float*)&z4;
#pragma unroll
        for (int dj = 0; dj < 7; dj++)
#pragma unroll
            for (int j = 0; j < 4; j++)
                acc[dj][j] = fmaf(zp[j], rw[j + dj + 1], acc[dj][j]);
    }
    __syncthreads();

    // cross-wave reduce (st aliased as red buffer)
    if (wid > 0) {
#pragma unroll
        for (int dj = 0; dj < 7; dj++) {
            float4 v = make_float4(acc[dj][0], acc[dj][1], acc[dj][2], acc[dj][3]);
            *(float4*)&st[((wid - 1) * 7 + dj) * 256 + lane * 4] = v;
        }
    }
    __syncthreads();
    if (wid == 0) {
#pragma unroll
        for (int s = 0; s < 3; s++)
#pragma unroll
            for (int dj = 0; dj < 7; dj++) {
                float4 v = *(const float4*)&st[(s * 7 + dj) * 256 + lane * 4];
                acc[dj][0] += v.x; acc[dj][1] += v.y;
                acc[dj][2] += v.z; acc[dj][3] += v.w;
            }
        // simp[cb][n][h0+r][k][w]
        float* sp = simp + ((((size_t)cb * N + n) * 64 + h0 + r) * KK) * 64;
#pragma unroll
        for (int dj = 0; dj < 7; dj++) {
            int k = di * 7 + dj;
            float4 v = make_float4(acc[dj][0], acc[dj][1], acc[dj][2], acc[dj][3]);
            *(float4*)&sp[(size_t)k * 64 + wpx] = v;
        }
    }
}

// ---------------------------------------------------------------------------
// K2.5: softmax with partial-sum fold.  Grid 512 = (n,h); 128 thr = 2 waves,
// wave ks splits k (0..24 / 25..48).  attn fp32 [n][h][k][w].
// ---------------------------------------------------------------------------
__global__ __launch_bounds__(128) void softk2(const float* __restrict__ simp,
                                              float* __restrict__ attn) {
    __shared__ float mred[2][64];
    __shared__ float sred[2][64];

    int row = blockIdx.x;            // n*64 + h
    int tid = threadIdx.x;
    int ks  = tid >> 6;
    int w   = tid & 63;
    int k0  = ks ? 25 : 0;
    int nk  = ks ? 24 : 25;

    float sv[25];
    float m = -1e30f;
    for (int i = 0; i < nk; i++) {
        int k = k0 + i;
        size_t off = ((size_t)row * KK + k) * 64 + w;
        float s = simp[off];
        s += simp[(size_t)1 * N * 64 * KK * 64 + off];
        s += simp[(size_t)2 * N * 64 * KK * 64 + off];
        s += simp[(size_t)3 * N * 64 * KK * 64 + off];
        sv[i] = s;
        m = fmaxf(m, s);
    }
    mred[ks][w] = m;
    __syncthreads();
    m = fmaxf(mred[0][w], mred[1][w]);
    float ssum = 0.f;
    for (int i = 0; i < nk; i++) {
        float e = __expf(sv[i] - m);
        sv[i] = e;
        ssum += e;
    }
    sred[ks][w] = ssum;
    __syncthreads();
    float inv = 1.f / (sred[0][w] + sred[1][w]);
    float* ap = attn + (size_t)row * KK * 64 + w;
    for (int i = 0; i < nk; i++)
        ap[(size_t)(k0 + i) * 64] = sv[i] * inv;
}

// ---------------------------------------------------------------------------
// K3: u[c](p) = sum_k attn_k(p) x_c(p+dk).
// Block = (cb 16-ch, n, row-pair): grid 2048 = 8cb x 8n x 32rp; 256 thr.
// x staged once (16c x 8 rows, c-major, 38.9 KB); attn read from global
// (L2-resident) as float4 per (di,dj).  Lane = (c_sub, r, w4): 2 channels,
// 4 px.  One barrier.
// ---------------------------------------------------------------------------
__global__ __launch_bounds__(256) void softpv5(const float* __restrict__ attn,
                                               const float* __restrict__ x,
                                               float* __restrict__ u) {
    __shared__ __align__(16) float st[16 * 8 * SLW];   // 9728 f = 38.9 KB

    int bid = blockIdx.x;
    int cb  = bid >> 8;            // 0..7 (16 channels each)
    int n   = (bid >> 5) & 7;
    int rp  = bid & 31;
    int h0  = rp * 2;

    int tid  = threadIdx.x;
    int wid  = tid >> 6;
    int lane = tid & 63;
    int c_sub = lane >> 5;
    int r     = (lane >> 4) & 1;
    int w4    = lane & 15;
    int wpx   = w4 * 4;

    const float* xb = x + (size_t)n * C * PIX;
    float* ub = u + (size_t)n * C * PIX;

    // halo zero + stage 16 c x 8 rows (h0-3 .. h0+4), c-major
    for (int idx = tid; idx < 16 * 8 * 8; idx += 256) {
        int col8 = idx & 7;
        int row  = (idx >> 3) & 7;
        int c    = idx >> 6;
        int col  = (col8 < 4) ? col8 : 64 + col8;
        st[(c * 8 + row) * SLW + col] = 0.f;
    }
#pragma unroll
    for (int i = 0; i < 8; i++) {
        int q   = tid + i * 256;
        int w16 = q & 15;
        int row = (q >> 4) & 7;
        int c   = q >> 7;             // 0..15
        int hh  = h0 - 3 + row;
        float4 v = make_float4(0.f, 0.f, 0.f, 0.f);
        if ((unsigned)hh < 64u)
            v = *(const float4*)&xb[(size_t)(cb * 16 + c) * PIX + hh * 64 + w16 * 4];
        *(float4*)&st[(c * 8 + row) * SLW + 4 + w16 * 4] = v;
    }
    __syncthreads();

    int clocal = wid * 4 + c_sub * 2;          // first of lane's 2 channels
    int cc0 = cb * 16 + clocal;
    const float* ap = attn + (((size_t)(n * 64 + h0 + r)) * KK) * 64 + wpx;

    float u4[2][4];
#pragma unroll
    for (int cl = 0; cl < 2; cl++)
#pragma unroll
        for (int j = 0; j < 4; j++) u4[cl][j] = 0.f;

#pragma unroll
    for (int di = 0; di < 7; di++) {
        float4 a4[7];
#pragma unroll
        for (int dj = 0; dj < 7; dj++)
            a4[dj] = *(const float4*)&ap[(size_t)(di * 7 + dj) * 64];
#pragma unroll
        for (int cl = 0; cl < 2; cl++) {
            const float* rp2 = &st[((clocal + cl) * 8 + r + di) * SLW + wpx];
            float rw[12];
            *(float4*)&rw[0] = *(const float4*)&rp2[0];
            *(float4*)&rw[4] = *(const float4*)&rp2[4];
            *(float4*)&rw[8] = *(const float4*)&rp2[8];
#pragma unroll
            for (int dj = 0; dj < 7; dj++) {
                const float* av = (const float*)&a4[dj];
#pragma unroll
                for (int j = 0; j < 4; j++)
                    u4[cl][j] = fmaf(av[j], rw[j + dj + 1], u4[cl][j]);
            }
        }
    }

#pragma unroll
    for (int cl = 0; cl < 2; cl++) {
        float4 v = make_float4(u4[cl][0], u4[cl][1], u4[cl][2], u4[cl][3]);
        *(float4*)&ub[(size_t)(cc0 + cl) * PIX + (h0 + r) * 64 + wpx] = v;
    }
}

// ---------------------------------------------------------------------------
extern "C" void kernel_launch(void* const* d_in, const int* in_sizes, int n_in,
                              void* d_out, int out_size, void* d_ws, size_t ws_size,
                              hipStream_t stream) {
    const float* x  = (const float*)d_in[0];
    const float* w1 = (const float*)d_in[1];
    const float* w2 = (const float*)d_in[2];
    const float* w3 = (const float*)d_in[3];
    float* wsf = (float*)d_ws;

    prep<<<68, 256, 0, stream>>>(w1, w2, w3, wsf + M_OFF, wsf + WT3_OFF);
    convk<<<512, 256, 0, stream>>>(wsf + M_OFF, x, wsf + Z_OFF);               // z = M^T x
    simk4<<<3584, 256, 0, stream>>>(wsf + Z_OFF, x, wsf + SIMP_OFF);           // partial sim
    softk2<<<512, 128, 0, stream>>>(wsf + SIMP_OFF, wsf + ATT_OFF);            // softmax
    softpv5<<<2048, 256, 0, stream>>>(wsf + ATT_OFF, x, wsf + U_OFF);          // u = PV(x)
    convk<<<512, 256, 0, stream>>>(wsf + WT3_OFF, wsf + U_OFF, (float*)d_out); // out = W3 u
}